// Round 1
// baseline (812.375 us; speedup 1.0000x reference)
//
#include <hip/hip_runtime.h>

// MultiFeatureMOE: soft-MoE, F=4 features, E=8 experts, B=4096, D=512, H=1024, O=512.
// Strategy: bf16 MFMA for both big GEMM families; gate softmax fp32; gate folded
// into GEMM1 epilogue; mean-over-f folded into gate; per-f pipeline with split-e
// atomic accumulation for GEMM2.

#define F_ 4
#define E_ 8
#define B_ 4096
#define D_ 512
#define H_ 1024
#define O_ 512

typedef unsigned short ushort_t;
typedef __bf16 bf16x8 __attribute__((ext_vector_type(8)));
typedef float f32x4 __attribute__((ext_vector_type(4)));

__device__ inline ushort_t f2bf(float f) {
  union { float f; unsigned u; } v; v.f = f;
  unsigned r = v.u + 0x7FFFu + ((v.u >> 16) & 1u);  // round-to-nearest-even
  return (ushort_t)(r >> 16);
}

// async global->LDS, 16B per lane. LDS dst = uniform base + lane*16 (HW rule).
__device__ inline void async16(const void* g, void* l) {
  __builtin_amdgcn_global_load_lds(
      (const __attribute__((address_space(1))) unsigned int*)g,
      (__attribute__((address_space(3))) unsigned int*)l, 16, 0, 0);
}

// ---------------- elementwise cast: features fp32 -> bf16 ----------------
__global__ void cast_feat_kernel(const float* __restrict__ in, ushort_t* __restrict__ out) {
  const int i = blockIdx.x * 256 + threadIdx.x;   // one float4 per thread
  const float4 v = ((const float4*)in)[i];
  ushort4 o;
  o.x = f2bf(v.x); o.y = f2bf(v.y); o.z = f2bf(v.z); o.w = f2bf(v.w);
  ((ushort4*)out)[i] = o;
}

// ------------- batched transpose+cast: [R][C] fp32 -> [C][R] bf16 -------------
__global__ void transpose_cast_kernel(const float* __restrict__ in, ushort_t* __restrict__ out,
                                      int R, int C) {
  __shared__ float tile[64][65];  // +1 pad: conflict-free transposed reads
  const size_t zoff = (size_t)blockIdx.z * R * C;
  in += zoff; out += zoff;
  const int tx = threadIdx.x & 63, ty = threadIdx.x >> 6;
  const int r0 = blockIdx.y * 64, c0 = blockIdx.x * 64;
#pragma unroll
  for (int i = 0; i < 16; ++i) {
    const int r = ty + i * 4;
    tile[r][tx] = in[(size_t)(r0 + r) * C + c0 + tx];
  }
  __syncthreads();
#pragma unroll
  for (int i = 0; i < 16; ++i) {
    const int c = ty + i * 4;
    out[(size_t)(c0 + c) * R + r0 + tx] = f2bf(tile[tx][c]);
  }
}

// ---------------- gate: g2[f,b,e] = softmax_e(feat.Wg + bg) / F ----------------
__global__ void gate_kernel(const float* __restrict__ features, const float* __restrict__ Wg,
                            const float* __restrict__ bg, float* __restrict__ g2) {
  const int fb = blockIdx.x;
  const int f = fb >> 12, b = fb & (B_ - 1);
  const int lane = threadIdx.x;
  const float* feat = features + ((size_t)f * B_ + b) * D_;
  const float* wg = Wg + (size_t)f * D_ * E_;
  float acc[E_] = {0.f, 0.f, 0.f, 0.f, 0.f, 0.f, 0.f, 0.f};
  for (int d = lane; d < D_; d += 64) {
    const float fv = feat[d];
    const float4 w0 = ((const float4*)(wg + d * E_))[0];
    const float4 w1 = ((const float4*)(wg + d * E_))[1];
    acc[0] += fv * w0.x; acc[1] += fv * w0.y; acc[2] += fv * w0.z; acc[3] += fv * w0.w;
    acc[4] += fv * w1.x; acc[5] += fv * w1.y; acc[6] += fv * w1.z; acc[7] += fv * w1.w;
  }
#pragma unroll
  for (int off = 32; off >= 1; off >>= 1)
#pragma unroll
    for (int e = 0; e < E_; ++e) acc[e] += __shfl_xor(acc[e], off, 64);
  float lg[E_], mx = -1e30f;
#pragma unroll
  for (int e = 0; e < E_; ++e) { lg[e] = acc[e] + bg[f * E_ + e]; mx = fmaxf(mx, lg[e]); }
  float s = 0.f;
#pragma unroll
  for (int e = 0; e < E_; ++e) { lg[e] = __expf(lg[e] - mx); s += lg[e]; }
  const float inv = 1.f / (s * (float)F_);
  if (lane < E_) g2[((size_t)f * B_ + b) * E_ + lane] = lg[lane] * inv;
}

// ---------------- GEMM1: h2 = g2 * relu(feat @ W1 + b1), per (f launch, e=z) ----------------
// A [B][D] bf16, Bt [E][H][D] bf16 (n-major), out Hf [B][E*H] bf16.
__global__ __launch_bounds__(256, 2) void gemm1_kernel(
    const ushort_t* __restrict__ A, const ushort_t* __restrict__ Bt,
    const float* __restrict__ b1, const float* __restrict__ g2,
    ushort_t* __restrict__ Hf) {
  __shared__ ushort_t As[128 * 32];
  __shared__ ushort_t Bs[128 * 32];
  const int e = blockIdx.z;
  const int n0 = blockIdx.x * 128;  // h
  const int m0 = blockIdx.y * 128;  // b
  const ushort_t* Bp = Bt + (size_t)e * H_ * D_;

  const int t = threadIdx.x, lane = t & 63, w = t >> 6;
  const int wm = w & 1, wn = w >> 1;
  const int lr = lane & 15, q = lane >> 4;

  // staging: wave w owns bytes [w*2048, w*2048+2048) of each 8KB tile
  const int so0 = w * 2048 + lane * 16, so1 = so0 + 1024;
  const int sr0 = so0 >> 6, sc0 = so0 & 63;
  const int sr1 = so1 >> 6, sc1 = so1 & 63;
  const char* aSrc0 = (const char*)A + ((size_t)(m0 + sr0) * D_) * 2 + sc0;
  const char* aSrc1 = (const char*)A + ((size_t)(m0 + sr1) * D_) * 2 + sc1;
  const char* bSrc0 = (const char*)Bp + ((size_t)(n0 + sr0) * D_) * 2 + sc0;
  const char* bSrc1 = (const char*)Bp + ((size_t)(n0 + sr1) * D_) * 2 + sc1;
  ushort_t* aDst0 = &As[w * 1024]; ushort_t* aDst1 = &As[w * 1024 + 512];
  ushort_t* bDst0 = &Bs[w * 1024]; ushort_t* bDst1 = &Bs[w * 1024 + 512];

  f32x4 acc[4][4];
#pragma unroll
  for (int i = 0; i < 4; ++i)
#pragma unroll
    for (int j = 0; j < 4; ++j) acc[i][j] = (f32x4){0.f, 0.f, 0.f, 0.f};

  for (int ks = 0; ks < D_ / 32; ++ks) {
    const int koff = ks * 64;  // 32 bf16 = 64 B
    async16(aSrc0 + koff, aDst0);
    async16(aSrc1 + koff, aDst1);
    async16(bSrc0 + koff, bDst0);
    async16(bSrc1 + koff, bDst1);
    __syncthreads();
    bf16x8 af[4], bfr[4];
#pragma unroll
    for (int i = 0; i < 4; ++i)
      af[i] = *(const bf16x8*)&As[(wm * 64 + i * 16 + lr) * 32 + q * 8];
#pragma unroll
    for (int j = 0; j < 4; ++j)
      bfr[j] = *(const bf16x8*)&Bs[(wn * 64 + j * 16 + lr) * 32 + q * 8];
#pragma unroll
    for (int i = 0; i < 4; ++i)
#pragma unroll
      for (int j = 0; j < 4; ++j)
        acc[i][j] = __builtin_amdgcn_mfma_f32_16x16x32_bf16(af[i], bfr[j], acc[i][j], 0, 0, 0);
    __syncthreads();
  }

  const float* b1e = b1 + (size_t)e * H_;
#pragma unroll
  for (int i = 0; i < 4; ++i) {
#pragma unroll
    for (int r = 0; r < 4; ++r) {
      const int m = m0 + wm * 64 + i * 16 + q * 4 + r;
      const float gv = g2[m * E_ + e];
#pragma unroll
      for (int j = 0; j < 4; ++j) {
        const int n = n0 + wn * 64 + j * 16 + lr;
        float v = acc[i][j][r] + b1e[n];
        v = fmaxf(v, 0.f) * gv;
        Hf[(size_t)m * (E_ * H_) + e * H_ + n] = f2bf(v);
      }
    }
  }
}

// ---------------- GEMM2: out += Hf @ W2t^T + g2*b2, split-K over e (z) ----------------
// A Hf [B][E*H] bf16, Bt [O][E*H] bf16, out [B][O] fp32 (atomic accumulate).
__global__ __launch_bounds__(256, 2) void gemm2_kernel(
    const ushort_t* __restrict__ Hf, const ushort_t* __restrict__ Bt,
    const float* __restrict__ b2, const float* __restrict__ g2,
    float* __restrict__ out) {
  __shared__ ushort_t As[128 * 32];
  __shared__ ushort_t Bs[128 * 32];
  const int e = blockIdx.z;
  const int n0 = blockIdx.x * 128;  // o
  const int m0 = blockIdx.y * 128;  // b
  const int EH = E_ * H_;
  const ushort_t* Ap = Hf + (size_t)e * H_;
  const ushort_t* Bp = Bt + (size_t)e * H_;

  const int t = threadIdx.x, lane = t & 63, w = t >> 6;
  const int wm = w & 1, wn = w >> 1;
  const int lr = lane & 15, q = lane >> 4;

  const int so0 = w * 2048 + lane * 16, so1 = so0 + 1024;
  const int sr0 = so0 >> 6, sc0 = so0 & 63;
  const int sr1 = so1 >> 6, sc1 = so1 & 63;
  const char* aSrc0 = (const char*)Ap + ((size_t)(m0 + sr0) * EH) * 2 + sc0;
  const char* aSrc1 = (const char*)Ap + ((size_t)(m0 + sr1) * EH) * 2 + sc1;
  const char* bSrc0 = (const char*)Bp + ((size_t)(n0 + sr0) * EH) * 2 + sc0;
  const char* bSrc1 = (const char*)Bp + ((size_t)(n0 + sr1) * EH) * 2 + sc1;
  ushort_t* aDst0 = &As[w * 1024]; ushort_t* aDst1 = &As[w * 1024 + 512];
  ushort_t* bDst0 = &Bs[w * 1024]; ushort_t* bDst1 = &Bs[w * 1024 + 512];

  f32x4 acc[4][4];
#pragma unroll
  for (int i = 0; i < 4; ++i)
#pragma unroll
    for (int j = 0; j < 4; ++j) acc[i][j] = (f32x4){0.f, 0.f, 0.f, 0.f};

  for (int ks = 0; ks < H_ / 32; ++ks) {
    const int koff = ks * 64;
    async16(aSrc0 + koff, aDst0);
    async16(aSrc1 + koff, aDst1);
    async16(bSrc0 + koff, bDst0);
    async16(bSrc1 + koff, bDst1);
    __syncthreads();
    bf16x8 af[4], bfr[4];
#pragma unroll
    for (int i = 0; i < 4; ++i)
      af[i] = *(const bf16x8*)&As[(wm * 64 + i * 16 + lr) * 32 + q * 8];
#pragma unroll
    for (int j = 0; j < 4; ++j)
      bfr[j] = *(const bf16x8*)&Bs[(wn * 64 + j * 16 + lr) * 32 + q * 8];
#pragma unroll
    for (int i = 0; i < 4; ++i)
#pragma unroll
      for (int j = 0; j < 4; ++j)
        acc[i][j] = __builtin_amdgcn_mfma_f32_16x16x32_bf16(af[i], bfr[j], acc[i][j], 0, 0, 0);
    __syncthreads();
  }

#pragma unroll
  for (int i = 0; i < 4; ++i) {
#pragma unroll
    for (int r = 0; r < 4; ++r) {
      const int m = m0 + wm * 64 + i * 16 + q * 4 + r;
      const float gv = g2[m * E_ + e];
#pragma unroll
      for (int j = 0; j < 4; ++j) {
        const int n = n0 + wn * 64 + j * 16 + lr;
        const float v = acc[i][j][r] + gv * b2[e * O_ + n];
        atomicAdd(&out[(size_t)m * O_ + n], v);
      }
    }
  }
}

extern "C" void kernel_launch(void* const* d_in, const int* in_sizes, int n_in,
                              void* d_out, int out_size, void* d_ws, size_t ws_size,
                              hipStream_t stream) {
  const float* features = (const float*)d_in[0];
  const float* W1 = (const float*)d_in[1];
  const float* b1 = (const float*)d_in[2];
  const float* W2 = (const float*)d_in[3];
  const float* b2 = (const float*)d_in[4];
  const float* Wg = (const float*)d_in[5];
  const float* bg = (const float*)d_in[6];
  float* out = (float*)d_out;

  char* ws = (char*)d_ws;
  ushort_t* featbf = (ushort_t*)ws;                                   // 16 MB
  ushort_t* w1t    = (ushort_t*)(ws + 16777216);                      // 32 MB [F][E][H][D]
  ushort_t* w2t    = (ushort_t*)(ws + 16777216 + 33554432);           // 32 MB [F][O][E*H]
  float*    g2     = (float*)(ws + 83886080);                         // 0.5 MB [F][B][E]
  ushort_t* Hf     = (ushort_t*)(ws + 84410368);                      // 64 MB [B][E*H], reused per f
  // total ws use: 151,519,232 B

  cast_feat_kernel<<<F_ * B_ * D_ / 1024, 256, 0, stream>>>(features, featbf);
  transpose_cast_kernel<<<dim3(H_ / 64, D_ / 64, F_ * E_), 256, 0, stream>>>(W1, w1t, D_, H_);
  transpose_cast_kernel<<<dim3(O_ / 64, (E_ * H_) / 64, F_), 256, 0, stream>>>(W2, w2t, E_ * H_, O_);
  gate_kernel<<<F_ * B_, 64, 0, stream>>>(features, Wg, bg, g2);
  hipMemsetAsync(d_out, 0, (size_t)B_ * O_ * sizeof(float), stream);

  for (int f = 0; f < F_; ++f) {
    gemm1_kernel<<<dim3(H_ / 128, B_ / 128, E_), 256, 0, stream>>>(
        featbf + (size_t)f * B_ * D_,
        w1t + (size_t)f * E_ * H_ * D_,
        b1 + (size_t)f * E_ * H_,
        g2 + (size_t)f * B_ * E_,
        Hf);
    gemm2_kernel<<<dim3(O_ / 128, B_ / 128, E_), 256, 0, stream>>>(
        Hf,
        w2t + (size_t)f * O_ * E_ * H_,
        b2 + (size_t)f * E_ * O_,
        g2 + (size_t)f * B_ * E_,
        out);
  }
}

// Round 2
// 809.828 us; speedup vs baseline: 1.0031x; 1.0031x over previous
//
#include <hip/hip_runtime.h>

// MultiFeatureMOE: F=4, E=8, B=4096, D=512, H=1024, O=512.
// Round 2: 64m x 512n wide-N tiles (A read once), XOR-swizzled LDS (conflict-free
// frag reads with async global_load_lds staging), split-e atomics for GEMM2.

#define F_ 4
#define E_ 8
#define B_ 4096
#define D_ 512
#define H_ 1024
#define O_ 512

typedef unsigned short ushort_t;
typedef __bf16 bf16x8 __attribute__((ext_vector_type(8)));
typedef float f32x4 __attribute__((ext_vector_type(4)));

__device__ inline ushort_t f2bf(float f) {
  union { float f; unsigned u; } v; v.f = f;
  unsigned r = v.u + 0x7FFFu + ((v.u >> 16) & 1u);  // RNE
  return (ushort_t)(r >> 16);
}

__device__ inline void async16(const void* g, void* l) {
  __builtin_amdgcn_global_load_lds(
      (const __attribute__((address_space(1))) unsigned int*)g,
      (__attribute__((address_space(3))) unsigned int*)l, 16, 0, 0);
}

// ---------------- elementwise cast: features fp32 -> bf16 ----------------
__global__ void cast_feat_kernel(const float* __restrict__ in, ushort_t* __restrict__ out) {
  const int i = blockIdx.x * 256 + threadIdx.x;
  const float4 v = ((const float4*)in)[i];
  ushort4 o;
  o.x = f2bf(v.x); o.y = f2bf(v.y); o.z = f2bf(v.z); o.w = f2bf(v.w);
  ((ushort4*)out)[i] = o;
}

// ------------- batched transpose+cast: [R][C] fp32 -> [C][R] bf16 -------------
__global__ void transpose_cast_kernel(const float* __restrict__ in, ushort_t* __restrict__ out,
                                      int R, int C) {
  __shared__ float tile[64][65];
  const size_t zoff = (size_t)blockIdx.z * R * C;
  in += zoff; out += zoff;
  const int tx = threadIdx.x & 63, ty = threadIdx.x >> 6;
  const int r0 = blockIdx.y * 64, c0 = blockIdx.x * 64;
#pragma unroll
  for (int i = 0; i < 16; ++i) {
    const int r = ty + i * 4;
    tile[r][tx] = in[(size_t)(r0 + r) * C + c0 + tx];
  }
  __syncthreads();
#pragma unroll
  for (int i = 0; i < 16; ++i) {
    const int c = ty + i * 4;
    out[(size_t)(c0 + c) * R + r0 + tx] = f2bf(tile[tx][c]);
  }
}

// ---------------- gate: g2[f,b,e] = softmax_e(feat.Wg + bg) / F ----------------
__global__ void gate_kernel(const float* __restrict__ features, const float* __restrict__ Wg,
                            const float* __restrict__ bg, float* __restrict__ g2) {
  const int fb = blockIdx.x;
  const int f = fb >> 12, b = fb & (B_ - 1);
  const int lane = threadIdx.x;
  const float* feat = features + ((size_t)f * B_ + b) * D_;
  const float* wg = Wg + (size_t)f * D_ * E_;
  float acc[E_] = {0.f, 0.f, 0.f, 0.f, 0.f, 0.f, 0.f, 0.f};
  for (int d = lane; d < D_; d += 64) {
    const float fv = feat[d];
    const float4 w0 = ((const float4*)(wg + d * E_))[0];
    const float4 w1 = ((const float4*)(wg + d * E_))[1];
    acc[0] += fv * w0.x; acc[1] += fv * w0.y; acc[2] += fv * w0.z; acc[3] += fv * w0.w;
    acc[4] += fv * w1.x; acc[5] += fv * w1.y; acc[6] += fv * w1.z; acc[7] += fv * w1.w;
  }
#pragma unroll
  for (int off = 32; off >= 1; off >>= 1)
#pragma unroll
    for (int e = 0; e < E_; ++e) acc[e] += __shfl_xor(acc[e], off, 64);
  float lg[E_], mx = -1e30f;
#pragma unroll
  for (int e = 0; e < E_; ++e) { lg[e] = acc[e] + bg[f * E_ + e]; mx = fmaxf(mx, lg[e]); }
  float s = 0.f;
#pragma unroll
  for (int e = 0; e < E_; ++e) { lg[e] = __expf(lg[e] - mx); s += lg[e]; }
  const float inv = 1.f / (s * (float)F_);
  if (lane < E_) g2[((size_t)f * B_ + b) * E_ + lane] = lg[lane] * inv;
}

// ============ shared GEMM engine: 64m x 512n, K-loop of 32-k steps ============
// LDS tiles XOR-swizzled at 16B granularity: logical (row r, chunk q) lives at
// physical chunk q ^ ((r>>1)&3). Staging applies the inverse on the GLOBAL side
// (k-invariant), so async16's fixed lane->LDS mapping is respected.

// ---------------- GEMM1: Hf[m][e*H+n] = bf16(g2 * relu(feat @ W1t + b1)) ----------------
__global__ __launch_bounds__(256, 2) void gemm1_kernel(
    const ushort_t* __restrict__ A, const ushort_t* __restrict__ Bt,
    const float* __restrict__ b1, const float* __restrict__ g2,
    __bf16* __restrict__ Hf) {
  __shared__ ushort_t As[64 * 32];    // 4 KB
  __shared__ ushort_t Bs[512 * 32];   // 32 KB
  const int e = blockIdx.z;
  const int n0 = blockIdx.x * 512;    // h-offset within H
  const int m0 = blockIdx.y * 64;
  const ushort_t* Bp = Bt + (size_t)e * H_ * D_;

  const int t = threadIdx.x, lane = t & 63, w = t >> 6;
  const int lr = lane & 15, q = lane >> 4;
  const int pc = q ^ ((lr >> 1) & 3);           // physical chunk for frag reads

  // staging geometry
  const int g = (t & 3) ^ ((t >> 3) & 3);       // swizzled global chunk
  const int arow = t >> 2;                      // 0..63
  const char* aSrc = (const char*)A + (size_t)(m0 + arow) * (D_ * 2) + g * 16;
  const char* bSrc[8];
#pragma unroll
  for (int i = 0; i < 8; ++i)
    bSrc[i] = (const char*)Bp + (size_t)(n0 + i * 64 + arow) * (D_ * 2) + g * 16;
  ushort_t* aDst = &As[(size_t)t * 8];
  ushort_t* bDst[8];
#pragma unroll
  for (int i = 0; i < 8; ++i) bDst[i] = &Bs[((size_t)i * 256 + t) * 8];

  f32x4 acc[4][8];
#pragma unroll
  for (int i = 0; i < 4; ++i)
#pragma unroll
    for (int j = 0; j < 8; ++j) acc[i][j] = (f32x4){0.f, 0.f, 0.f, 0.f};

  for (int ks = 0; ks < D_ / 32; ++ks) {
    async16(aSrc, aDst);
#pragma unroll
    for (int i = 0; i < 8; ++i) async16(bSrc[i], bDst[i]);
    aSrc += 64;
#pragma unroll
    for (int i = 0; i < 8; ++i) bSrc[i] += 64;
    __syncthreads();
    bf16x8 af[4], bfr[8];
#pragma unroll
    for (int i = 0; i < 4; ++i)
      af[i] = *(const bf16x8*)&As[(i * 16 + lr) * 32 + pc * 8];
#pragma unroll
    for (int j = 0; j < 8; ++j)
      bfr[j] = *(const bf16x8*)&Bs[(w * 128 + j * 16 + lr) * 32 + pc * 8];
#pragma unroll
    for (int i = 0; i < 4; ++i)
#pragma unroll
      for (int j = 0; j < 8; ++j)
        acc[i][j] = __builtin_amdgcn_mfma_f32_16x16x32_bf16(af[i], bfr[j], acc[i][j], 0, 0, 0);
    __syncthreads();
  }

  const float* b1e = b1 + (size_t)e * H_;
#pragma unroll
  for (int i = 0; i < 4; ++i) {
#pragma unroll
    for (int r = 0; r < 4; ++r) {
      const int m = m0 + i * 16 + q * 4 + r;
      const float gv = g2[m * E_ + e];
#pragma unroll
      for (int j = 0; j < 8; ++j) {
        const int n = n0 + w * 128 + j * 16 + lr;
        float v = acc[i][j][r] + b1e[n];
        v = fmaxf(v, 0.f) * gv;
        Hf[(size_t)m * (E_ * H_) + e * H_ + n] = (__bf16)v;
      }
    }
  }
}

// ---------------- GEMM2: out[m][n] += Hf_e @ W2t_e + g2*b2 (atomic over e) ----------------
__global__ __launch_bounds__(256, 2) void gemm2_kernel(
    const ushort_t* __restrict__ Hf, const ushort_t* __restrict__ Bt,
    const float* __restrict__ b2, const float* __restrict__ g2,
    float* __restrict__ out) {
  __shared__ ushort_t As[64 * 32];
  __shared__ ushort_t Bs[512 * 32];
  const int e = blockIdx.z;
  const int m0 = blockIdx.y * 64;
  const int EH = E_ * H_;

  const int t = threadIdx.x, lane = t & 63, w = t >> 6;
  const int lr = lane & 15, q = lane >> 4;
  const int pc = q ^ ((lr >> 1) & 3);

  const int g = (t & 3) ^ ((t >> 3) & 3);
  const int arow = t >> 2;
  const char* aSrc = (const char*)Hf + (size_t)(m0 + arow) * (EH * 2) + e * (H_ * 2) + g * 16;
  const char* bSrc[8];
#pragma unroll
  for (int i = 0; i < 8; ++i)
    bSrc[i] = (const char*)Bt + (size_t)(i * 64 + arow) * (EH * 2) + e * (H_ * 2) + g * 16;
  ushort_t* aDst = &As[(size_t)t * 8];
  ushort_t* bDst[8];
#pragma unroll
  for (int i = 0; i < 8; ++i) bDst[i] = &Bs[((size_t)i * 256 + t) * 8];

  f32x4 acc[4][8];
#pragma unroll
  for (int i = 0; i < 4; ++i)
#pragma unroll
    for (int j = 0; j < 8; ++j) acc[i][j] = (f32x4){0.f, 0.f, 0.f, 0.f};

  for (int ks = 0; ks < H_ / 32; ++ks) {
    async16(aSrc, aDst);
#pragma unroll
    for (int i = 0; i < 8; ++i) async16(bSrc[i], bDst[i]);
    aSrc += 64;
#pragma unroll
    for (int i = 0; i < 8; ++i) bSrc[i] += 64;
    __syncthreads();
    bf16x8 af[4], bfr[8];
#pragma unroll
    for (int i = 0; i < 4; ++i)
      af[i] = *(const bf16x8*)&As[(i * 16 + lr) * 32 + pc * 8];
#pragma unroll
    for (int j = 0; j < 8; ++j)
      bfr[j] = *(const bf16x8*)&Bs[(w * 128 + j * 16 + lr) * 32 + pc * 8];
#pragma unroll
    for (int i = 0; i < 4; ++i)
#pragma unroll
      for (int j = 0; j < 8; ++j)
        acc[i][j] = __builtin_amdgcn_mfma_f32_16x16x32_bf16(af[i], bfr[j], acc[i][j], 0, 0, 0);
    __syncthreads();
  }

#pragma unroll
  for (int i = 0; i < 4; ++i) {
#pragma unroll
    for (int r = 0; r < 4; ++r) {
      const int m = m0 + i * 16 + q * 4 + r;
      const float gv = g2[m * E_ + e];
#pragma unroll
      for (int j = 0; j < 8; ++j) {
        const int n = w * 128 + j * 16 + lr;
        const float v = acc[i][j][r] + gv * b2[e * O_ + n];
        atomicAdd(&out[(size_t)m * O_ + n], v);
      }
    }
  }
}

extern "C" void kernel_launch(void* const* d_in, const int* in_sizes, int n_in,
                              void* d_out, int out_size, void* d_ws, size_t ws_size,
                              hipStream_t stream) {
  const float* features = (const float*)d_in[0];
  const float* W1 = (const float*)d_in[1];
  const float* b1 = (const float*)d_in[2];
  const float* W2 = (const float*)d_in[3];
  const float* b2 = (const float*)d_in[4];
  const float* Wg = (const float*)d_in[5];
  const float* bg = (const float*)d_in[6];
  float* out = (float*)d_out;

  char* ws = (char*)d_ws;
  ushort_t* featbf = (ushort_t*)ws;                                   // 16 MB [F][B][D]
  ushort_t* w1t    = (ushort_t*)(ws + 16777216);                      // 32 MB [F][E][H][D]
  ushort_t* w2t    = (ushort_t*)(ws + 16777216 + 33554432);           // 32 MB [F][O][E*H]
  float*    g2     = (float*)(ws + 83886080);                         // 0.5 MB [F][B][E]
  ushort_t* Hf     = (ushort_t*)(ws + 84410368);                      // 64 MB [B][E*H], reused per f

  cast_feat_kernel<<<F_ * B_ * D_ / 1024, 256, 0, stream>>>(features, featbf);
  transpose_cast_kernel<<<dim3(H_ / 64, D_ / 64, F_ * E_), 256, 0, stream>>>(W1, w1t, D_, H_);
  transpose_cast_kernel<<<dim3(O_ / 64, (E_ * H_) / 64, F_), 256, 0, stream>>>(W2, w2t, E_ * H_, O_);
  gate_kernel<<<F_ * B_, 64, 0, stream>>>(features, Wg, bg, g2);
  hipMemsetAsync(d_out, 0, (size_t)B_ * O_ * sizeof(float), stream);

  for (int f = 0; f < F_; ++f) {
    gemm1_kernel<<<dim3(H_ / 512, B_ / 64, E_), 256, 0, stream>>>(
        featbf + (size_t)f * B_ * D_,
        w1t + (size_t)f * E_ * H_ * D_,
        b1 + (size_t)f * E_ * H_,
        g2 + (size_t)f * B_ * E_,
        (__bf16*)Hf);
    gemm2_kernel<<<dim3(1, B_ / 64, E_), 256, 0, stream>>>(
        Hf,
        w2t + (size_t)f * O_ * E_ * H_,
        b2 + (size_t)f * E_ * O_,
        g2 + (size_t)f * B_ * E_,
        out);
  }
}

// Round 3
// 669.692 us; speedup vs baseline: 1.2131x; 1.2093x over previous
//
#include <hip/hip_runtime.h>

// MultiFeatureMOE: F=4, E=8, B=4096, D=512, H=1024, O=512.
// Round 3: 128x128 m97-shape GEMMs, contiguous feeds ([E][B][H] Hf, [F][E][O][H] W2),
// XOR-swizzled LDS (0 conflicts), XCD-grouped experts, atomic-free gemm2
// (per-e fp32 partials + reduce kernel, ws-size fallback to atomics).

#define F_ 4
#define E_ 8
#define B_ 4096
#define D_ 512
#define H_ 1024
#define O_ 512

typedef unsigned short ushort_t;
typedef __bf16 bf16x8 __attribute__((ext_vector_type(8)));
typedef float f32x4 __attribute__((ext_vector_type(4)));

__device__ inline ushort_t f2bf(float f) {
  union { float f; unsigned u; } v; v.f = f;
  unsigned r = v.u + 0x7FFFu + ((v.u >> 16) & 1u);  // RNE
  return (ushort_t)(r >> 16);
}

__device__ inline void async16(const void* g, void* l) {
  __builtin_amdgcn_global_load_lds(
      (const __attribute__((address_space(1))) unsigned int*)g,
      (__attribute__((address_space(3))) unsigned int*)l, 16, 0, 0);
}

// ---------------- elementwise cast: features fp32 -> bf16 ----------------
__global__ void cast_feat_kernel(const float* __restrict__ in, ushort_t* __restrict__ out) {
  const int i = blockIdx.x * 256 + threadIdx.x;
  const float4 v = ((const float4*)in)[i];
  ushort4 o;
  o.x = f2bf(v.x); o.y = f2bf(v.y); o.z = f2bf(v.z); o.w = f2bf(v.w);
  ((ushort4*)out)[i] = o;
}

// ------------- batched transpose+cast: [R][C] fp32 -> [C][R] bf16 -------------
__global__ void transpose_cast_kernel(const float* __restrict__ in, ushort_t* __restrict__ out,
                                      int R, int C) {
  __shared__ float tile[64][65];
  const size_t zoff = (size_t)blockIdx.z * R * C;
  in += zoff; out += zoff;
  const int tx = threadIdx.x & 63, ty = threadIdx.x >> 6;
  const int r0 = blockIdx.y * 64, c0 = blockIdx.x * 64;
#pragma unroll
  for (int i = 0; i < 16; ++i) {
    const int r = ty + i * 4;
    tile[r][tx] = in[(size_t)(r0 + r) * C + c0 + tx];
  }
  __syncthreads();
#pragma unroll
  for (int i = 0; i < 16; ++i) {
    const int c = ty + i * 4;
    out[(size_t)(c0 + c) * R + r0 + tx] = f2bf(tile[tx][c]);
  }
}

// ---------------- gate: g2[f,b,e] = softmax_e(feat.Wg + bg) / F ----------------
__global__ void gate_kernel(const float* __restrict__ features, const float* __restrict__ Wg,
                            const float* __restrict__ bg, float* __restrict__ g2) {
  const int fb = blockIdx.x;
  const int f = fb >> 12, b = fb & (B_ - 1);
  const int lane = threadIdx.x;
  const float* feat = features + ((size_t)f * B_ + b) * D_;
  const float* wg = Wg + (size_t)f * D_ * E_;
  float acc[E_] = {0.f, 0.f, 0.f, 0.f, 0.f, 0.f, 0.f, 0.f};
  for (int d = lane; d < D_; d += 64) {
    const float fv = feat[d];
    const float4 w0 = ((const float4*)(wg + d * E_))[0];
    const float4 w1 = ((const float4*)(wg + d * E_))[1];
    acc[0] += fv * w0.x; acc[1] += fv * w0.y; acc[2] += fv * w0.z; acc[3] += fv * w0.w;
    acc[4] += fv * w1.x; acc[5] += fv * w1.y; acc[6] += fv * w1.z; acc[7] += fv * w1.w;
  }
#pragma unroll
  for (int off = 32; off >= 1; off >>= 1)
#pragma unroll
    for (int e = 0; e < E_; ++e) acc[e] += __shfl_xor(acc[e], off, 64);
  float lg[E_], mx = -1e30f;
#pragma unroll
  for (int e = 0; e < E_; ++e) { lg[e] = acc[e] + bg[f * E_ + e]; mx = fmaxf(mx, lg[e]); }
  float s = 0.f;
#pragma unroll
  for (int e = 0; e < E_; ++e) { lg[e] = __expf(lg[e] - mx); s += lg[e]; }
  const float inv = 1.f / (s * (float)F_);
  if (lane < E_) g2[((size_t)f * B_ + b) * E_ + lane] = lg[lane] * inv;
}

// ---------------- GEMM1: Hf[e][m][n] = bf16(g2 * relu(feat @ W1t_e + b1_e)) ----------------
// A [B][D] contiguous, Bt [E][H][D] contiguous rows. 128x128 tile, BK=32, 16 steps.
__global__ __launch_bounds__(256, 3) void gemm1_kernel(
    const ushort_t* __restrict__ A, const ushort_t* __restrict__ Bt,
    const float* __restrict__ b1, const float* __restrict__ g2,
    ushort_t* __restrict__ Hf) {
  __shared__ ushort_t As[128 * 32];
  __shared__ ushort_t Bs[128 * 32];
  const int id = blockIdx.x;
  const int e = id & 7;           // expert per XCD (id%8 heuristic)
  const int s = id >> 3;          // 0..255
  const int n0 = (s & 7) * 128;   // h
  const int m0 = (s >> 3) * 128;  // b
  const ushort_t* Bp = Bt + (size_t)e * H_ * D_;

  const int t = threadIdx.x, lane = t & 63, w = t >> 6;
  const int wm = w & 1, wn = w >> 1;
  const int lr = lane & 15, q = lane >> 4;
  const int pc = q ^ ((lr >> 1) & 3);

  const int r0 = t >> 2;                         // 0..63
  const int g = (t & 3) ^ ((r0 >> 1) & 3);       // swizzled global chunk
  const char* aSrc0 = (const char*)A + (size_t)(m0 + r0) * (D_ * 2) + g * 16;
  const char* aSrc1 = (const char*)A + (size_t)(m0 + r0 + 64) * (D_ * 2) + g * 16;
  const char* bSrc0 = (const char*)Bp + (size_t)(n0 + r0) * (D_ * 2) + g * 16;
  const char* bSrc1 = (const char*)Bp + (size_t)(n0 + r0 + 64) * (D_ * 2) + g * 16;
  ushort_t* aDst0 = &As[t * 8];  ushort_t* aDst1 = &As[2048 + t * 8];
  ushort_t* bDst0 = &Bs[t * 8];  ushort_t* bDst1 = &Bs[2048 + t * 8];

  f32x4 acc[4][4];
#pragma unroll
  for (int i = 0; i < 4; ++i)
#pragma unroll
    for (int j = 0; j < 4; ++j) acc[i][j] = (f32x4){0.f, 0.f, 0.f, 0.f};

  for (int ks = 0; ks < D_ / 32; ++ks) {
    async16(aSrc0, aDst0); async16(aSrc1, aDst1);
    async16(bSrc0, bDst0); async16(bSrc1, bDst1);
    aSrc0 += 64; aSrc1 += 64; bSrc0 += 64; bSrc1 += 64;
    __syncthreads();
    bf16x8 af[4], bfr[4];
#pragma unroll
    for (int i = 0; i < 4; ++i)
      af[i] = *(const bf16x8*)&As[(wm * 64 + i * 16 + lr) * 32 + pc * 8];
#pragma unroll
    for (int j = 0; j < 4; ++j)
      bfr[j] = *(const bf16x8*)&Bs[(wn * 64 + j * 16 + lr) * 32 + pc * 8];
#pragma unroll
    for (int i = 0; i < 4; ++i)
#pragma unroll
      for (int j = 0; j < 4; ++j)
        acc[i][j] = __builtin_amdgcn_mfma_f32_16x16x32_bf16(af[i], bfr[j], acc[i][j], 0, 0, 0);
    __syncthreads();
  }

  const float* b1e = b1 + (size_t)e * H_;
#pragma unroll
  for (int i = 0; i < 4; ++i) {
#pragma unroll
    for (int r = 0; r < 4; ++r) {
      const int m = m0 + wm * 64 + i * 16 + q * 4 + r;
      const float gv = g2[m * E_ + e];
#pragma unroll
      for (int j = 0; j < 4; ++j) {
        const int n = n0 + wn * 64 + j * 16 + lr;
        float v = acc[i][j][r] + b1e[n];
        v = fmaxf(v, 0.f) * gv;
        Hf[((size_t)e * B_ + m) * H_ + n] = f2bf(v);
      }
    }
  }
}

// ---------------- GEMM2: part[e][m][n] = Hf_e @ W2t_e + g2*b2 (or atomic to out) ----------------
// A Hf [E][B][H] contiguous rows, Bt w2t [E][O][H] contiguous rows. 128x128, BK=32, 32 steps.
__global__ __launch_bounds__(256, 3) void gemm2_kernel(
    const ushort_t* __restrict__ Hf, const ushort_t* __restrict__ Bt,
    const float* __restrict__ b2, const float* __restrict__ g2,
    float* __restrict__ part, float* __restrict__ out) {
  __shared__ ushort_t As[128 * 32];
  __shared__ ushort_t Bs[128 * 32];
  const int id = blockIdx.x;
  const int e = id & 7;
  const int s = id >> 3;          // 0..127
  const int n0 = (s & 3) * 128;   // o
  const int m0 = (s >> 2) * 128;  // b
  const ushort_t* Ap = Hf + (size_t)e * B_ * H_;
  const ushort_t* Bp = Bt + (size_t)e * O_ * H_;

  const int t = threadIdx.x, lane = t & 63, w = t >> 6;
  const int wm = w & 1, wn = w >> 1;
  const int lr = lane & 15, q = lane >> 4;
  const int pc = q ^ ((lr >> 1) & 3);

  const int r0 = t >> 2;
  const int g = (t & 3) ^ ((r0 >> 1) & 3);
  const char* aSrc0 = (const char*)Ap + (size_t)(m0 + r0) * (H_ * 2) + g * 16;
  const char* aSrc1 = (const char*)Ap + (size_t)(m0 + r0 + 64) * (H_ * 2) + g * 16;
  const char* bSrc0 = (const char*)Bp + (size_t)(n0 + r0) * (H_ * 2) + g * 16;
  const char* bSrc1 = (const char*)Bp + (size_t)(n0 + r0 + 64) * (H_ * 2) + g * 16;
  ushort_t* aDst0 = &As[t * 8];  ushort_t* aDst1 = &As[2048 + t * 8];
  ushort_t* bDst0 = &Bs[t * 8];  ushort_t* bDst1 = &Bs[2048 + t * 8];

  f32x4 acc[4][4];
#pragma unroll
  for (int i = 0; i < 4; ++i)
#pragma unroll
    for (int j = 0; j < 4; ++j) acc[i][j] = (f32x4){0.f, 0.f, 0.f, 0.f};

  for (int ks = 0; ks < H_ / 32; ++ks) {
    async16(aSrc0, aDst0); async16(aSrc1, aDst1);
    async16(bSrc0, bDst0); async16(bSrc1, bDst1);
    aSrc0 += 64; aSrc1 += 64; bSrc0 += 64; bSrc1 += 64;
    __syncthreads();
    bf16x8 af[4], bfr[4];
#pragma unroll
    for (int i = 0; i < 4; ++i)
      af[i] = *(const bf16x8*)&As[(wm * 64 + i * 16 + lr) * 32 + pc * 8];
#pragma unroll
    for (int j = 0; j < 4; ++j)
      bfr[j] = *(const bf16x8*)&Bs[(wn * 64 + j * 16 + lr) * 32 + pc * 8];
#pragma unroll
    for (int i = 0; i < 4; ++i)
#pragma unroll
      for (int j = 0; j < 4; ++j)
        acc[i][j] = __builtin_amdgcn_mfma_f32_16x16x32_bf16(af[i], bfr[j], acc[i][j], 0, 0, 0);
    __syncthreads();
  }

  const float* b2e = b2 + (size_t)e * O_;
#pragma unroll
  for (int i = 0; i < 4; ++i) {
#pragma unroll
    for (int r = 0; r < 4; ++r) {
      const int m = m0 + wm * 64 + i * 16 + q * 4 + r;
      const float gv = g2[m * E_ + e];
#pragma unroll
      for (int j = 0; j < 4; ++j) {
        const int n = n0 + wn * 64 + j * 16 + lr;
        const float v = acc[i][j][r] + gv * b2e[n];
        if (part) part[((size_t)e * B_ + m) * O_ + n] = v;
        else atomicAdd(&out[(size_t)m * O_ + n], v);
      }
    }
  }
}

// ---------------- reduce: out += sum_e part[e] ----------------
__global__ void reduce_kernel(const float4* __restrict__ part, float4* __restrict__ out) {
  const int p = blockIdx.x * 256 + threadIdx.x;
  float4 s = part[p];
#pragma unroll
  for (int e = 1; e < E_; ++e) {
    const float4 v = part[(size_t)e * (B_ * O_ / 4) + p];
    s.x += v.x; s.y += v.y; s.z += v.z; s.w += v.w;
  }
  float4 o = out[p];
  o.x += s.x; o.y += s.y; o.z += s.z; o.w += s.w;
  out[p] = o;
}

extern "C" void kernel_launch(void* const* d_in, const int* in_sizes, int n_in,
                              void* d_out, int out_size, void* d_ws, size_t ws_size,
                              hipStream_t stream) {
  const float* features = (const float*)d_in[0];
  const float* W1 = (const float*)d_in[1];
  const float* b1 = (const float*)d_in[2];
  const float* W2 = (const float*)d_in[3];
  const float* b2 = (const float*)d_in[4];
  const float* Wg = (const float*)d_in[5];
  const float* bg = (const float*)d_in[6];
  float* out = (float*)d_out;

  char* ws = (char*)d_ws;
  ushort_t* featbf = (ushort_t*)ws;                       // 16 MB  [F][B][D]
  ushort_t* w1t    = (ushort_t*)(ws + 16777216);          // 32 MB  [F][E][H][D]
  ushort_t* w2t    = (ushort_t*)(ws + 50331648);          // 32 MB  [F][E][O][H]
  float*    g2     = (float*)(ws + 83886080);             // 0.5 MB [F][B][E]
  ushort_t* Hf     = (ushort_t*)(ws + 84410368);          // 64 MB  [E][B][H], reused per f
  float*    part   = (float*)(ws + 151519232);            // 64 MB  [E][B][O]
  const bool big = ws_size >= (size_t)218628096;
  float* partArg = big ? part : nullptr;

  cast_feat_kernel<<<F_ * B_ * D_ / 1024, 256, 0, stream>>>(features, featbf);
  transpose_cast_kernel<<<dim3(H_ / 64, D_ / 64, F_ * E_), 256, 0, stream>>>(W1, w1t, D_, H_);
  transpose_cast_kernel<<<dim3(O_ / 64, H_ / 64, F_ * E_), 256, 0, stream>>>(W2, w2t, H_, O_);
  gate_kernel<<<F_ * B_, 64, 0, stream>>>(features, Wg, bg, g2);
  hipMemsetAsync(d_out, 0, (size_t)B_ * O_ * sizeof(float), stream);

  for (int f = 0; f < F_; ++f) {
    gemm1_kernel<<<(B_ / 128) * (H_ / 128) * E_, 256, 0, stream>>>(
        featbf + (size_t)f * B_ * D_,
        w1t + (size_t)f * E_ * H_ * D_,
        b1 + (size_t)f * E_ * H_,
        g2 + (size_t)f * B_ * E_,
        Hf);
    gemm2_kernel<<<(B_ / 128) * (O_ / 128) * E_, 256, 0, stream>>>(
        Hf,
        w2t + (size_t)f * E_ * O_ * H_,
        b2 + (size_t)f * E_ * O_,
        g2 + (size_t)f * B_ * E_,
        partArg, out);
    if (big)
      reduce_kernel<<<B_ * O_ / 4 / 256, 256, 0, stream>>>((const float4*)part, (float4*)out);
  }
}

// Round 4
// 669.229 us; speedup vs baseline: 1.2139x; 1.0007x over previous
//
#include <hip/hip_runtime.h>

// MultiFeatureMOE: F=4, E=8, B=4096, D=512, H=1024, O=512.
// Round 4: LDS-staged coalesced epilogues (dwordx4 stores), gemm2 covers 2 experts
// per block (K=2048), bf16 partials [F][4][B][O], single final reduce, 13 launches.

#define F_ 4
#define E_ 8
#define B_ 4096
#define D_ 512
#define H_ 1024
#define O_ 512

typedef unsigned short ushort_t;
typedef __bf16 bf16x8 __attribute__((ext_vector_type(8)));
typedef float f32x4 __attribute__((ext_vector_type(4)));
typedef unsigned short ushort8_t __attribute__((ext_vector_type(8)));

__device__ inline ushort_t f2bf(float f) {
  union { float f; unsigned u; } v; v.f = f;
  unsigned r = v.u + 0x7FFFu + ((v.u >> 16) & 1u);  // RNE
  return (ushort_t)(r >> 16);
}
__device__ inline float bf2f(ushort_t u) {
  union { unsigned u; float f; } v; v.u = ((unsigned)u) << 16;
  return v.f;
}

__device__ inline void async16(const void* g, void* l) {
  __builtin_amdgcn_global_load_lds(
      (const __attribute__((address_space(1))) unsigned int*)g,
      (__attribute__((address_space(3))) unsigned int*)l, 16, 0, 0);
}

// ---------------- elementwise cast: features fp32 -> bf16 ----------------
__global__ void cast_feat_kernel(const float* __restrict__ in, ushort_t* __restrict__ out) {
  const int i = blockIdx.x * 256 + threadIdx.x;
  const float4 v = ((const float4*)in)[i];
  ushort4 o;
  o.x = f2bf(v.x); o.y = f2bf(v.y); o.z = f2bf(v.z); o.w = f2bf(v.w);
  ((ushort4*)out)[i] = o;
}

// ------------- batched transpose+cast: [R][C] fp32 -> [C][R] bf16 -------------
__global__ void transpose_cast_kernel(const float* __restrict__ in, ushort_t* __restrict__ out,
                                      int R, int C) {
  __shared__ float tile[64][65];
  const size_t zoff = (size_t)blockIdx.z * R * C;
  in += zoff; out += zoff;
  const int tx = threadIdx.x & 63, ty = threadIdx.x >> 6;
  const int r0 = blockIdx.y * 64, c0 = blockIdx.x * 64;
#pragma unroll
  for (int i = 0; i < 16; ++i) {
    const int r = ty + i * 4;
    tile[r][tx] = in[(size_t)(r0 + r) * C + c0 + tx];
  }
  __syncthreads();
#pragma unroll
  for (int i = 0; i < 16; ++i) {
    const int c = ty + i * 4;
    out[(size_t)(c0 + c) * R + r0 + tx] = f2bf(tile[tx][c]);
  }
}

// ---------------- gate: g2[f,b,e] = softmax_e(feat.Wg + bg) / F ----------------
__global__ void gate_kernel(const float* __restrict__ features, const float* __restrict__ Wg,
                            const float* __restrict__ bg, float* __restrict__ g2) {
  const int fb = blockIdx.x;
  const int f = fb >> 12, b = fb & (B_ - 1);
  const int lane = threadIdx.x;
  const float* feat = features + ((size_t)f * B_ + b) * D_;
  const float* wg = Wg + (size_t)f * D_ * E_;
  float acc[E_] = {0.f, 0.f, 0.f, 0.f, 0.f, 0.f, 0.f, 0.f};
  for (int d = lane; d < D_; d += 64) {
    const float fv = feat[d];
    const float4 w0 = ((const float4*)(wg + d * E_))[0];
    const float4 w1 = ((const float4*)(wg + d * E_))[1];
    acc[0] += fv * w0.x; acc[1] += fv * w0.y; acc[2] += fv * w0.z; acc[3] += fv * w0.w;
    acc[4] += fv * w1.x; acc[5] += fv * w1.y; acc[6] += fv * w1.z; acc[7] += fv * w1.w;
  }
#pragma unroll
  for (int off = 32; off >= 1; off >>= 1)
#pragma unroll
    for (int e = 0; e < E_; ++e) acc[e] += __shfl_xor(acc[e], off, 64);
  float lg[E_], mx = -1e30f;
#pragma unroll
  for (int e = 0; e < E_; ++e) { lg[e] = acc[e] + bg[f * E_ + e]; mx = fmaxf(mx, lg[e]); }
  float s = 0.f;
#pragma unroll
  for (int e = 0; e < E_; ++e) { lg[e] = __expf(lg[e] - mx); s += lg[e]; }
  const float inv = 1.f / (s * (float)F_);
  if (lane < E_) g2[((size_t)f * B_ + b) * E_ + lane] = lg[lane] * inv;
}

// Epilogue LDS tile: 128 rows x 136 ushort stride (272 B: 16B-aligned rows).
#define EPI_STRIDE 136

// ---------------- GEMM1: Hf[e][m][n] = bf16(g2 * relu(feat @ W1t_e + b1_e)) ----------------
__global__ __launch_bounds__(256, 3) void gemm1_kernel(
    const ushort_t* __restrict__ A, const ushort_t* __restrict__ Bt,
    const float* __restrict__ b1, const float* __restrict__ g2,
    ushort_t* __restrict__ Hf) {
  __shared__ __align__(16) ushort_t smem[128 * EPI_STRIDE];  // 34816 B; staging uses first 16 KB
  ushort_t* As = smem;          // 4096 ushorts
  ushort_t* Bs = smem + 4096;   // 4096 ushorts
  const int id = blockIdx.x;
  const int e = id & 7;
  const int s = id >> 3;
  const int n0 = (s & 7) * 128;   // h
  const int m0 = (s >> 3) * 128;  // b
  const ushort_t* Bp = Bt + (size_t)e * H_ * D_;

  const int t = threadIdx.x, lane = t & 63, w = t >> 6;
  const int wm = w & 1, wn = w >> 1;
  const int lr = lane & 15, q = lane >> 4;
  const int pc = q ^ ((lr >> 1) & 3);

  const int r0 = t >> 2;
  const int g = (t & 3) ^ ((r0 >> 1) & 3);
  const char* aSrc0 = (const char*)A + (size_t)(m0 + r0) * (D_ * 2) + g * 16;
  const char* aSrc1 = (const char*)A + (size_t)(m0 + r0 + 64) * (D_ * 2) + g * 16;
  const char* bSrc0 = (const char*)Bp + (size_t)(n0 + r0) * (D_ * 2) + g * 16;
  const char* bSrc1 = (const char*)Bp + (size_t)(n0 + r0 + 64) * (D_ * 2) + g * 16;
  ushort_t* aDst0 = &As[t * 8];  ushort_t* aDst1 = &As[2048 + t * 8];
  ushort_t* bDst0 = &Bs[t * 8];  ushort_t* bDst1 = &Bs[2048 + t * 8];

  f32x4 acc[4][4];
#pragma unroll
  for (int i = 0; i < 4; ++i)
#pragma unroll
    for (int j = 0; j < 4; ++j) acc[i][j] = (f32x4){0.f, 0.f, 0.f, 0.f};

  for (int ks = 0; ks < D_ / 32; ++ks) {
    async16(aSrc0, aDst0); async16(aSrc1, aDst1);
    async16(bSrc0, bDst0); async16(bSrc1, bDst1);
    aSrc0 += 64; aSrc1 += 64; bSrc0 += 64; bSrc1 += 64;
    __syncthreads();
    bf16x8 af[4], bfr[4];
#pragma unroll
    for (int i = 0; i < 4; ++i)
      af[i] = *(const bf16x8*)&As[(wm * 64 + i * 16 + lr) * 32 + pc * 8];
#pragma unroll
    for (int j = 0; j < 4; ++j)
      bfr[j] = *(const bf16x8*)&Bs[(wn * 64 + j * 16 + lr) * 32 + pc * 8];
#pragma unroll
    for (int i = 0; i < 4; ++i)
#pragma unroll
      for (int j = 0; j < 4; ++j)
        acc[i][j] = __builtin_amdgcn_mfma_f32_16x16x32_bf16(af[i], bfr[j], acc[i][j], 0, 0, 0);
    __syncthreads();
  }

  // epilogue: bias+relu+gate, stage bf16 tile in LDS, coalesced dwordx4 stores
  const float* b1e = b1 + (size_t)e * H_;
#pragma unroll
  for (int i = 0; i < 4; ++i) {
#pragma unroll
    for (int r = 0; r < 4; ++r) {
      const int ml = wm * 64 + i * 16 + q * 4 + r;
      const float gv = g2[(m0 + ml) * E_ + e];
#pragma unroll
      for (int j = 0; j < 4; ++j) {
        const int nl = wn * 64 + j * 16 + lr;
        float v = acc[i][j][r] + b1e[n0 + nl];
        v = fmaxf(v, 0.f) * gv;
        smem[ml * EPI_STRIDE + nl] = f2bf(v);
      }
    }
  }
  __syncthreads();
  const int row = t >> 1, half = t & 1;
  const ushort_t* src = &smem[row * EPI_STRIDE + half * 64];
  ushort_t* dst = Hf + ((size_t)e * B_ + m0 + row) * H_ + n0 + half * 64;
#pragma unroll
  for (int c = 0; c < 8; ++c)
    *(ushort8_t*)(dst + c * 8) = *(const ushort8_t*)(src + c * 8);
}

// ---------------- GEMM2: part[grp] = sum_{e in grp} Hf_e @ W2t_e + g*b2 (bf16 partials) ----------------
// 2 experts per block, K=2048 (64 steps). grid 512 = (B/128)*(O/128)*4 groups.
__global__ __launch_bounds__(256, 3) void gemm2_kernel(
    const ushort_t* __restrict__ Hf, const ushort_t* __restrict__ Bt,
    const float* __restrict__ b2, const float* __restrict__ g2,
    ushort_t* __restrict__ part) {
  __shared__ __align__(16) ushort_t smem[128 * EPI_STRIDE];
  ushort_t* As = smem;
  ushort_t* Bs = smem + 4096;
  const int id = blockIdx.x;
  const int grp = id & 3;
  const int s = id >> 2;          // 0..127
  const int n0 = (s & 3) * 128;   // o
  const int m0 = (s >> 2) * 128;  // b
  const int e0 = grp * 2;

  const int t = threadIdx.x, lane = t & 63, w = t >> 6;
  const int wm = w & 1, wn = w >> 1;
  const int lr = lane & 15, q = lane >> 4;
  const int pc = q ^ ((lr >> 1) & 3);

  const int r0 = t >> 2;
  const int g = (t & 3) ^ ((r0 >> 1) & 3);
  ushort_t* aDst0 = &As[t * 8];  ushort_t* aDst1 = &As[2048 + t * 8];
  ushort_t* bDst0 = &Bs[t * 8];  ushort_t* bDst1 = &Bs[2048 + t * 8];

  f32x4 acc[4][4];
#pragma unroll
  for (int i = 0; i < 4; ++i)
#pragma unroll
    for (int j = 0; j < 4; ++j) acc[i][j] = (f32x4){0.f, 0.f, 0.f, 0.f};

  for (int h = 0; h < 2; ++h) {
    const int e = e0 + h;
    const ushort_t* Ap = Hf + (size_t)e * B_ * H_;
    const ushort_t* Bp = Bt + (size_t)e * O_ * H_;
    const char* aSrc0 = (const char*)Ap + (size_t)(m0 + r0) * (H_ * 2) + g * 16;
    const char* aSrc1 = (const char*)Ap + (size_t)(m0 + r0 + 64) * (H_ * 2) + g * 16;
    const char* bSrc0 = (const char*)Bp + (size_t)(n0 + r0) * (H_ * 2) + g * 16;
    const char* bSrc1 = (const char*)Bp + (size_t)(n0 + r0 + 64) * (H_ * 2) + g * 16;
    for (int ks = 0; ks < H_ / 32; ++ks) {
      async16(aSrc0, aDst0); async16(aSrc1, aDst1);
      async16(bSrc0, bDst0); async16(bSrc1, bDst1);
      aSrc0 += 64; aSrc1 += 64; bSrc0 += 64; bSrc1 += 64;
      __syncthreads();
      bf16x8 af[4], bfr[4];
#pragma unroll
      for (int i = 0; i < 4; ++i)
        af[i] = *(const bf16x8*)&As[(wm * 64 + i * 16 + lr) * 32 + pc * 8];
#pragma unroll
      for (int j = 0; j < 4; ++j)
        bfr[j] = *(const bf16x8*)&Bs[(wn * 64 + j * 16 + lr) * 32 + pc * 8];
#pragma unroll
      for (int i = 0; i < 4; ++i)
#pragma unroll
        for (int j = 0; j < 4; ++j)
          acc[i][j] = __builtin_amdgcn_mfma_f32_16x16x32_bf16(af[i], bfr[j], acc[i][j], 0, 0, 0);
      __syncthreads();
    }
  }

  // epilogue: add gate-weighted b2 for both experts, bf16, LDS-staged stores
  const float* b2e0 = b2 + (size_t)e0 * O_;
  const float* b2e1 = b2e0 + O_;
#pragma unroll
  for (int i = 0; i < 4; ++i) {
#pragma unroll
    for (int r = 0; r < 4; ++r) {
      const int ml = wm * 64 + i * 16 + q * 4 + r;
      const float gv0 = g2[(m0 + ml) * E_ + e0];
      const float gv1 = g2[(m0 + ml) * E_ + e0 + 1];
#pragma unroll
      for (int j = 0; j < 4; ++j) {
        const int nl = wn * 64 + j * 16 + lr;
        const int n = n0 + nl;
        const float v = acc[i][j][r] + gv0 * b2e0[n] + gv1 * b2e1[n];
        smem[ml * EPI_STRIDE + nl] = f2bf(v);
      }
    }
  }
  __syncthreads();
  const int row = t >> 1, half = t & 1;
  const ushort_t* src = &smem[row * EPI_STRIDE + half * 64];
  ushort_t* dst = part + (size_t)grp * (B_ * O_) + ((size_t)(m0 + row)) * O_ + n0 + half * 64;
#pragma unroll
  for (int c = 0; c < 8; ++c)
    *(ushort8_t*)(dst + c * 8) = *(const ushort8_t*)(src + c * 8);
}

// ---------------- final reduce: out = sum over 16 bf16 slabs ----------------
__global__ void reduce_kernel(const ushort_t* __restrict__ part, float* __restrict__ out) {
  const size_t p = ((size_t)blockIdx.x * 256 + threadIdx.x) * 8;
  float s[8] = {0.f, 0.f, 0.f, 0.f, 0.f, 0.f, 0.f, 0.f};
#pragma unroll
  for (int k = 0; k < F_ * 4; ++k) {
    const ushort8_t u = *(const ushort8_t*)&part[(size_t)k * (B_ * O_) + p];
#pragma unroll
    for (int j = 0; j < 8; ++j) s[j] += bf2f(u[j]);
  }
  float4 o0 = {s[0], s[1], s[2], s[3]}, o1 = {s[4], s[5], s[6], s[7]};
  *(float4*)&out[p] = o0;
  *(float4*)&out[p + 4] = o1;
}

extern "C" void kernel_launch(void* const* d_in, const int* in_sizes, int n_in,
                              void* d_out, int out_size, void* d_ws, size_t ws_size,
                              hipStream_t stream) {
  const float* features = (const float*)d_in[0];
  const float* W1 = (const float*)d_in[1];
  const float* b1 = (const float*)d_in[2];
  const float* W2 = (const float*)d_in[3];
  const float* b2 = (const float*)d_in[4];
  const float* Wg = (const float*)d_in[5];
  const float* bg = (const float*)d_in[6];
  float* out = (float*)d_out;

  char* ws = (char*)d_ws;
  ushort_t* featbf = (ushort_t*)ws;                       // 16 MB   [F][B][D]
  ushort_t* w1t    = (ushort_t*)(ws + 16777216);          // 32 MB   [F][E][H][D]
  ushort_t* w2t    = (ushort_t*)(ws + 50331648);          // 32 MB   [F][E][O][H]
  float*    g2     = (float*)(ws + 83886080);             // 0.5 MB  [F][B][E]
  ushort_t* Hf     = (ushort_t*)(ws + 84410368);          // 64 MB   [E][B][H], reused per f
  ushort_t* part   = (ushort_t*)(ws + 151519232);         // 64 MB   [F][4][B][O] bf16
  // end: 218628096 B (verified available in round 3)

  cast_feat_kernel<<<F_ * B_ * D_ / 1024, 256, 0, stream>>>(features, featbf);
  transpose_cast_kernel<<<dim3(H_ / 64, D_ / 64, F_ * E_), 256, 0, stream>>>(W1, w1t, D_, H_);
  transpose_cast_kernel<<<dim3(O_ / 64, H_ / 64, F_ * E_), 256, 0, stream>>>(W2, w2t, H_, O_);
  gate_kernel<<<F_ * B_, 64, 0, stream>>>(features, Wg, bg, g2);

  for (int f = 0; f < F_; ++f) {
    gemm1_kernel<<<(B_ / 128) * (H_ / 128) * E_, 256, 0, stream>>>(
        featbf + (size_t)f * B_ * D_,
        w1t + (size_t)f * E_ * H_ * D_,
        b1 + (size_t)f * E_ * H_,
        g2 + (size_t)f * B_ * E_,
        Hf);
    gemm2_kernel<<<(B_ / 128) * (O_ / 128) * 4, 256, 0, stream>>>(
        Hf,
        w2t + (size_t)f * E_ * O_ * H_,
        b2 + (size_t)f * E_ * O_,
        g2 + (size_t)f * B_ * E_,
        part + (size_t)f * 4 * B_ * O_);
  }
  reduce_kernel<<<B_ * O_ / 8 / 256, 256, 0, stream>>>(part, out);
}

// Round 5
// 652.950 us; speedup vs baseline: 1.2442x; 1.0249x over previous
//
#include <hip/hip_runtime.h>

// MultiFeatureMOE: F=4, E=8, B=4096, D=512, H=1024, O=512.
// Round 5: swapped-operand MFMA (transposed C layout) -> register-packed
// coalesced epilogues (ushort4 stores), LDS back to 16 KB, launch_bounds(256,4).
// gemm2: 2 experts/block K=2048, bf16 partials, single final reduce.

#define F_ 4
#define E_ 8
#define B_ 4096
#define D_ 512
#define H_ 1024
#define O_ 512

typedef unsigned short ushort_t;
typedef __bf16 bf16x8 __attribute__((ext_vector_type(8)));
typedef float f32x4 __attribute__((ext_vector_type(4)));
typedef unsigned short ushort8_t __attribute__((ext_vector_type(8)));

__device__ inline ushort_t f2bf(float f) {
  union { float f; unsigned u; } v; v.f = f;
  unsigned r = v.u + 0x7FFFu + ((v.u >> 16) & 1u);  // RNE
  return (ushort_t)(r >> 16);
}
__device__ inline float bf2f(ushort_t u) {
  union { unsigned u; float f; } v; v.u = ((unsigned)u) << 16;
  return v.f;
}

__device__ inline void async16(const void* g, void* l) {
  __builtin_amdgcn_global_load_lds(
      (const __attribute__((address_space(1))) unsigned int*)g,
      (__attribute__((address_space(3))) unsigned int*)l, 16, 0, 0);
}

// ---------------- elementwise cast: features fp32 -> bf16 ----------------
__global__ void cast_feat_kernel(const float* __restrict__ in, ushort_t* __restrict__ out) {
  const int i = blockIdx.x * 256 + threadIdx.x;
  const float4 v = ((const float4*)in)[i];
  ushort4 o;
  o.x = f2bf(v.x); o.y = f2bf(v.y); o.z = f2bf(v.z); o.w = f2bf(v.w);
  ((ushort4*)out)[i] = o;
}

// ------------- batched transpose+cast: [R][C] fp32 -> [C][R] bf16 -------------
__global__ void transpose_cast_kernel(const float* __restrict__ in, ushort_t* __restrict__ out,
                                      int R, int C) {
  __shared__ float tile[64][65];
  const size_t zoff = (size_t)blockIdx.z * R * C;
  in += zoff; out += zoff;
  const int tx = threadIdx.x & 63, ty = threadIdx.x >> 6;
  const int r0 = blockIdx.y * 64, c0 = blockIdx.x * 64;
#pragma unroll
  for (int i = 0; i < 16; ++i) {
    const int r = ty + i * 4;
    tile[r][tx] = in[(size_t)(r0 + r) * C + c0 + tx];
  }
  __syncthreads();
#pragma unroll
  for (int i = 0; i < 16; ++i) {
    const int c = ty + i * 4;
    out[(size_t)(c0 + c) * R + r0 + tx] = f2bf(tile[tx][c]);
  }
}

// ---------------- gate: g2[f,b,e] = softmax_e(feat.Wg + bg) / F ----------------
__global__ void gate_kernel(const float* __restrict__ features, const float* __restrict__ Wg,
                            const float* __restrict__ bg, float* __restrict__ g2) {
  const int fb = blockIdx.x;
  const int f = fb >> 12, b = fb & (B_ - 1);
  const int lane = threadIdx.x;
  const float* feat = features + ((size_t)f * B_ + b) * D_;
  const float* wg = Wg + (size_t)f * D_ * E_;
  float acc[E_] = {0.f, 0.f, 0.f, 0.f, 0.f, 0.f, 0.f, 0.f};
  for (int d = lane; d < D_; d += 64) {
    const float fv = feat[d];
    const float4 w0 = ((const float4*)(wg + d * E_))[0];
    const float4 w1 = ((const float4*)(wg + d * E_))[1];
    acc[0] += fv * w0.x; acc[1] += fv * w0.y; acc[2] += fv * w0.z; acc[3] += fv * w0.w;
    acc[4] += fv * w1.x; acc[5] += fv * w1.y; acc[6] += fv * w1.z; acc[7] += fv * w1.w;
  }
#pragma unroll
  for (int off = 32; off >= 1; off >>= 1)
#pragma unroll
    for (int e = 0; e < E_; ++e) acc[e] += __shfl_xor(acc[e], off, 64);
  float lg[E_], mx = -1e30f;
#pragma unroll
  for (int e = 0; e < E_; ++e) { lg[e] = acc[e] + bg[f * E_ + e]; mx = fmaxf(mx, lg[e]); }
  float s = 0.f;
#pragma unroll
  for (int e = 0; e < E_; ++e) { lg[e] = __expf(lg[e] - mx); s += lg[e]; }
  const float inv = 1.f / (s * (float)F_);
  if (lane < E_) g2[((size_t)f * B_ + b) * E_ + lane] = lg[lane] * inv;
}

// ---------------- GEMM1: Hf[e][m][n] = bf16(g2 * relu(feat @ W1t_e + b1_e)) ----------------
// Swapped-operand MFMA: acc[i][j] holds n = j*16+q*4+{0..3} at m = i*16+lr.
__global__ __launch_bounds__(256, 4) void gemm1_kernel(
    const ushort_t* __restrict__ A, const ushort_t* __restrict__ Bt,
    const float* __restrict__ b1, const float* __restrict__ g2,
    ushort_t* __restrict__ Hf) {
  __shared__ ushort_t As[128 * 32];
  __shared__ ushort_t Bs[128 * 32];
  const int id = blockIdx.x;
  const int e = id & 7;
  const int s = id >> 3;
  const int n0 = (s & 7) * 128;   // h
  const int m0 = (s >> 3) * 128;  // b
  const ushort_t* Bp = Bt + (size_t)e * H_ * D_;

  const int t = threadIdx.x, lane = t & 63, w = t >> 6;
  const int wm = w & 1, wn = w >> 1;
  const int lr = lane & 15, q = lane >> 4;
  const int pc = q ^ ((lr >> 1) & 3);

  const int r0 = t >> 2;
  const int g = (t & 3) ^ ((r0 >> 1) & 3);
  const char* aSrc0 = (const char*)A + (size_t)(m0 + r0) * (D_ * 2) + g * 16;
  const char* aSrc1 = (const char*)A + (size_t)(m0 + r0 + 64) * (D_ * 2) + g * 16;
  const char* bSrc0 = (const char*)Bp + (size_t)(n0 + r0) * (D_ * 2) + g * 16;
  const char* bSrc1 = (const char*)Bp + (size_t)(n0 + r0 + 64) * (D_ * 2) + g * 16;
  ushort_t* aDst0 = &As[t * 8];  ushort_t* aDst1 = &As[2048 + t * 8];
  ushort_t* bDst0 = &Bs[t * 8];  ushort_t* bDst1 = &Bs[2048 + t * 8];

  f32x4 acc[4][4];
#pragma unroll
  for (int i = 0; i < 4; ++i)
#pragma unroll
    for (int j = 0; j < 4; ++j) acc[i][j] = (f32x4){0.f, 0.f, 0.f, 0.f};

  for (int ks = 0; ks < D_ / 32; ++ks) {
    async16(aSrc0, aDst0); async16(aSrc1, aDst1);
    async16(bSrc0, bDst0); async16(bSrc1, bDst1);
    aSrc0 += 64; aSrc1 += 64; bSrc0 += 64; bSrc1 += 64;
    __syncthreads();
    bf16x8 af[4], bfr[4];
#pragma unroll
    for (int i = 0; i < 4; ++i)
      af[i] = *(const bf16x8*)&As[(wm * 64 + i * 16 + lr) * 32 + pc * 8];
#pragma unroll
    for (int j = 0; j < 4; ++j)
      bfr[j] = *(const bf16x8*)&Bs[(wn * 64 + j * 16 + lr) * 32 + pc * 8];
#pragma unroll
    for (int i = 0; i < 4; ++i)
#pragma unroll
      for (int j = 0; j < 4; ++j)
        acc[i][j] = __builtin_amdgcn_mfma_f32_16x16x32_bf16(bfr[j], af[i], acc[i][j], 0, 0, 0);
    __syncthreads();
  }

  // register epilogue: m = i*16+lr fixed per i; n = j*16+q*4+{0..3} -> ushort4 store
  const float* b1e = b1 + (size_t)e * H_;
#pragma unroll
  for (int i = 0; i < 4; ++i) {
    const int m = m0 + wm * 64 + i * 16 + lr;
    const float gv = g2[m * E_ + e];
    ushort_t* dstRow = Hf + ((size_t)e * B_ + m) * H_ + n0 + wn * 64 + q * 4;
#pragma unroll
    for (int j = 0; j < 4; ++j) {
      const int n = n0 + wn * 64 + j * 16 + q * 4;
      const float4 bb = *(const float4*)&b1e[n];
      ushort4 o;
      o.x = f2bf(fmaxf(acc[i][j][0] + bb.x, 0.f) * gv);
      o.y = f2bf(fmaxf(acc[i][j][1] + bb.y, 0.f) * gv);
      o.z = f2bf(fmaxf(acc[i][j][2] + bb.z, 0.f) * gv);
      o.w = f2bf(fmaxf(acc[i][j][3] + bb.w, 0.f) * gv);
      *(ushort4*)(dstRow + j * 16) = o;
    }
  }
}

// ---------------- GEMM2: part[grp] = sum_{e in grp} Hf_e @ W2t_e + g*b2 (bf16) ----------------
__global__ __launch_bounds__(256, 4) void gemm2_kernel(
    const ushort_t* __restrict__ Hf, const ushort_t* __restrict__ Bt,
    const float* __restrict__ b2, const float* __restrict__ g2,
    ushort_t* __restrict__ part) {
  __shared__ ushort_t As[128 * 32];
  __shared__ ushort_t Bs[128 * 32];
  const int id = blockIdx.x;
  const int grp = id & 3;
  const int s = id >> 2;
  const int n0 = (s & 3) * 128;   // o
  const int m0 = (s >> 2) * 128;  // b
  const int e0 = grp * 2;

  const int t = threadIdx.x, lane = t & 63, w = t >> 6;
  const int wm = w & 1, wn = w >> 1;
  const int lr = lane & 15, q = lane >> 4;
  const int pc = q ^ ((lr >> 1) & 3);

  const int r0 = t >> 2;
  const int g = (t & 3) ^ ((r0 >> 1) & 3);
  ushort_t* aDst0 = &As[t * 8];  ushort_t* aDst1 = &As[2048 + t * 8];
  ushort_t* bDst0 = &Bs[t * 8];  ushort_t* bDst1 = &Bs[2048 + t * 8];

  f32x4 acc[4][4];
#pragma unroll
  for (int i = 0; i < 4; ++i)
#pragma unroll
    for (int j = 0; j < 4; ++j) acc[i][j] = (f32x4){0.f, 0.f, 0.f, 0.f};

  for (int h = 0; h < 2; ++h) {
    const int e = e0 + h;
    const ushort_t* Ap = Hf + (size_t)e * B_ * H_;
    const ushort_t* Bp = Bt + (size_t)e * O_ * H_;
    const char* aSrc0 = (const char*)Ap + (size_t)(m0 + r0) * (H_ * 2) + g * 16;
    const char* aSrc1 = (const char*)Ap + (size_t)(m0 + r0 + 64) * (H_ * 2) + g * 16;
    const char* bSrc0 = (const char*)Bp + (size_t)(n0 + r0) * (H_ * 2) + g * 16;
    const char* bSrc1 = (const char*)Bp + (size_t)(n0 + r0 + 64) * (H_ * 2) + g * 16;
    for (int ks = 0; ks < H_ / 32; ++ks) {
      async16(aSrc0, aDst0); async16(aSrc1, aDst1);
      async16(bSrc0, bDst0); async16(bSrc1, bDst1);
      aSrc0 += 64; aSrc1 += 64; bSrc0 += 64; bSrc1 += 64;
      __syncthreads();
      bf16x8 af[4], bfr[4];
#pragma unroll
      for (int i = 0; i < 4; ++i)
        af[i] = *(const bf16x8*)&As[(wm * 64 + i * 16 + lr) * 32 + pc * 8];
#pragma unroll
      for (int j = 0; j < 4; ++j)
        bfr[j] = *(const bf16x8*)&Bs[(wn * 64 + j * 16 + lr) * 32 + pc * 8];
#pragma unroll
      for (int i = 0; i < 4; ++i)
#pragma unroll
        for (int j = 0; j < 4; ++j)
          acc[i][j] = __builtin_amdgcn_mfma_f32_16x16x32_bf16(bfr[j], af[i], acc[i][j], 0, 0, 0);
      __syncthreads();
    }
  }

  const float* b2e0 = b2 + (size_t)e0 * O_;
  const float* b2e1 = b2e0 + O_;
#pragma unroll
  for (int i = 0; i < 4; ++i) {
    const int m = m0 + wm * 64 + i * 16 + lr;
    const float gv0 = g2[m * E_ + e0];
    const float gv1 = g2[m * E_ + e0 + 1];
    ushort_t* dstRow = part + (size_t)grp * (B_ * O_) + (size_t)m * O_ + n0 + wn * 64 + q * 4;
#pragma unroll
    for (int j = 0; j < 4; ++j) {
      const int n = n0 + wn * 64 + j * 16 + q * 4;
      const float4 c0 = *(const float4*)&b2e0[n];
      const float4 c1 = *(const float4*)&b2e1[n];
      ushort4 o;
      o.x = f2bf(acc[i][j][0] + gv0 * c0.x + gv1 * c1.x);
      o.y = f2bf(acc[i][j][1] + gv0 * c0.y + gv1 * c1.y);
      o.z = f2bf(acc[i][j][2] + gv0 * c0.z + gv1 * c1.z);
      o.w = f2bf(acc[i][j][3] + gv0 * c0.w + gv1 * c1.w);
      *(ushort4*)(dstRow + j * 16) = o;
    }
  }
}

// ---------------- final reduce: out = sum over 16 bf16 slabs ----------------
__global__ void reduce_kernel(const ushort_t* __restrict__ part, float* __restrict__ out) {
  const size_t p = ((size_t)blockIdx.x * 256 + threadIdx.x) * 8;
  float s[8] = {0.f, 0.f, 0.f, 0.f, 0.f, 0.f, 0.f, 0.f};
#pragma unroll
  for (int k = 0; k < F_ * 4; ++k) {
    const ushort8_t u = *(const ushort8_t*)&part[(size_t)k * (B_ * O_) + p];
#pragma unroll
    for (int j = 0; j < 8; ++j) s[j] += bf2f(u[j]);
  }
  float4 o0 = {s[0], s[1], s[2], s[3]}, o1 = {s[4], s[5], s[6], s[7]};
  *(float4*)&out[p] = o0;
  *(float4*)&out[p + 4] = o1;
}

extern "C" void kernel_launch(void* const* d_in, const int* in_sizes, int n_in,
                              void* d_out, int out_size, void* d_ws, size_t ws_size,
                              hipStream_t stream) {
  const float* features = (const float*)d_in[0];
  const float* W1 = (const float*)d_in[1];
  const float* b1 = (const float*)d_in[2];
  const float* W2 = (const float*)d_in[3];
  const float* b2 = (const float*)d_in[4];
  const float* Wg = (const float*)d_in[5];
  const float* bg = (const float*)d_in[6];
  float* out = (float*)d_out;

  char* ws = (char*)d_ws;
  ushort_t* featbf = (ushort_t*)ws;                       // 16 MB   [F][B][D]
  ushort_t* w1t    = (ushort_t*)(ws + 16777216);          // 32 MB   [F][E][H][D]
  ushort_t* w2t    = (ushort_t*)(ws + 50331648);          // 32 MB   [F][E][O][H]
  float*    g2     = (float*)(ws + 83886080);             // 0.5 MB  [F][B][E]
  ushort_t* Hf     = (ushort_t*)(ws + 84410368);          // 64 MB   [E][B][H], reused per f
  ushort_t* part   = (ushort_t*)(ws + 151519232);         // 64 MB   [F][4][B][O] bf16

  cast_feat_kernel<<<F_ * B_ * D_ / 1024, 256, 0, stream>>>(features, featbf);
  transpose_cast_kernel<<<dim3(H_ / 64, D_ / 64, F_ * E_), 256, 0, stream>>>(W1, w1t, D_, H_);
  transpose_cast_kernel<<<dim3(O_ / 64, H_ / 64, F_ * E_), 256, 0, stream>>>(W2, w2t, H_, O_);
  gate_kernel<<<F_ * B_, 64, 0, stream>>>(features, Wg, bg, g2);

  for (int f = 0; f < F_; ++f) {
    gemm1_kernel<<<(B_ / 128) * (H_ / 128) * E_, 256, 0, stream>>>(
        featbf + (size_t)f * B_ * D_,
        w1t + (size_t)f * E_ * H_ * D_,
        b1 + (size_t)f * E_ * H_,
        g2 + (size_t)f * B_ * E_,
        Hf);
    gemm2_kernel<<<(B_ / 128) * (O_ / 128) * 4, 256, 0, stream>>>(
        Hf,
        w2t + (size_t)f * E_ * O_ * H_,
        b2 + (size_t)f * E_ * O_,
        g2 + (size_t)f * B_ * E_,
        part + (size_t)f * 4 * B_ * O_);
  }
  reduce_kernel<<<B_ * O_ / 8 / 256, 256, 0, stream>>>(part, out);
}